// Round 14
// baseline (69.711 us; speedup 1.0000x reference)
//
#include <hip/hip_runtime.h>
#include <hip/hip_bf16.h>

typedef __bf16 bf16_t;
typedef bf16_t bf16x8 __attribute__((ext_vector_type(8)));
typedef bf16_t bf16x4 __attribute__((ext_vector_type(4)));
typedef float f32x4 __attribute__((ext_vector_type(4)));

#define MFMA16(a, b, c) __builtin_amdgcn_mfma_f32_16x16x32_bf16((a), (b), (c), 0, 0, 0)

// B=8, T=2048, E=1024, H=128
#define TT 2048
#define EE 1024
#define HH 128
#define UPB 288   // partial slots per batch: sum over 64 qtiles of (qt>>3)+1

typedef __attribute__((address_space(3))) void lds_void_t;
typedef const __attribute__((address_space(1))) void gbl_void_t;

// Fragment-major layouts (every consumer load = one coalesced 64x16B instr):
//  Wf: chunk(ct,kt): lane(g,c) elem e = W_{ct>>3}[k=kt*32+g*8+e][n=(ct&7)*16+c]
//  Qf/Kf: chunk(grt,kk): lane(g,c) elem e = M[grt*16+c][kk*32+g*8+e]
//  Vf: chunk(b,vc,hb): lane(g,c) elem j = V[b][vc*32+g*8+j][hb*16+c]

// ---------------- prep: Wf fragment-major, f32 -> bf16 ----------------
__global__ __launch_bounds__(256) void prep_w_kernel(
    const float* __restrict__ Wq, const float* __restrict__ Wk,
    const float* __restrict__ Wv, bf16_t* __restrict__ Wf)
{
    int idx = blockIdx.x * 256 + threadIdx.x;   // 0 .. 393215
    int e  = idx & 7;
    int c  = (idx >> 3) & 15;
    int g  = (idx >> 7) & 3;
    int kt = (idx >> 9) & 31;
    int ct = idx >> 14;                          // 0..23
    int w  = ct >> 3;
    const float* W = (w == 0) ? Wq : (w == 1) ? Wk : Wv;
    int k = kt * 32 + g * 8 + e;
    int n = (ct & 7) * 16 + c;
    Wf[idx] = (bf16_t)W[k * HH + n];
}

// ---------------- fused QKV GEMM: [16384 x 1024] x [1024 x 384] ----------------
// m97/T3 structure: 512 blocks (2/CU, co-resident pairs share x via same-XCD
// mapping) x 256 thr (4 waves, wave 32x96); BM=64, BN=192, BK=32.
// x staged f32 via global_load_lds(16B): linear LDS dest + inverse-swizzled
// SOURCE + swizzled ds_read (rule #21, conflict-free). LDS double-buffered;
// stage(t+1) issued BEFORE compute(t); ONE __syncthreads per K-tile (its
// vmcnt0 drain makes buf^1 ready). W frags fragment-major, double-reg-buffered.
__global__ __launch_bounds__(256) void qkv_kernel(
    const float* __restrict__ x, const bf16_t* __restrict__ Wf,
    bf16_t* __restrict__ Qf, bf16_t* __restrict__ Kf, bf16_t* __restrict__ Vf)
{
    __shared__ __attribute__((aligned(16))) float As[2][64][32];  // 2 x 8 KB
    const int bx = blockIdx.x;
    const int row0  = (bx & 255) * 64;
    const int nhalf = bx >> 8;                   // bx, bx+256 share x band, same XCD
    const int tid  = threadIdx.x;
    const int lane = tid & 63;
    const int wid  = tid >> 6;
    const int wm = wid >> 1, wn = wid & 1;       // wave = 32 rows x 96 cols
    const int g = lane >> 4, c = lane & 15;

    // staging: lane l -> LDS row wid*8 + is*32 + (l>>3), 16B-slot l&7 (linear);
    // source pre-swizzled: slot' = (l&7) ^ ((l>>3)&7)
    const int srow  = wid * 8 + (lane >> 3);
    const int sslot = (lane & 7) ^ ((lane >> 3) & 7);
    const float* xsrc0 = x + (size_t)(row0 + srow) * EE + sslot * 4;
    const float* xsrc1 = x + (size_t)(row0 + srow + 32) * EE + sslot * 4;

#define STAGE(BUF, T) do {                                                    \
    __builtin_amdgcn_global_load_lds((gbl_void_t*)(xsrc0 + (size_t)(T) * 32), \
        (lds_void_t*)((char*)&As[BUF][0][0] + wid * 1024), 16, 0, 0);         \
    __builtin_amdgcn_global_load_lds((gbl_void_t*)(xsrc1 + (size_t)(T) * 32), \
        (lds_void_t*)((char*)&As[BUF][0][0] + wid * 1024 + 4096), 16, 0, 0);  \
} while (0)

    // W fragment base: wave wn covers ct = nhalf*12 + wn*6 .. +5
    const bf16_t* wfbase = Wf + ((size_t)(nhalf * 12 + wn * 6) * 32) * 512 + lane * 8;
    bf16x8 w[2][6];
#define WLOAD(S, T)                                                           \
    for (int nt = 0; nt < 6; ++nt)                                            \
        w[S][nt] = *(const bf16x8*)(wfbase + ((size_t)nt * 32 + (T)) * 512);

    f32x4 acc[2][6];
    for (int i = 0; i < 2; ++i)
        for (int j = 0; j < 6; ++j) acc[i][j] = (f32x4)0.0f;

#define COMPUTE(BUF, S) do {                                                  \
    for (int mt = 0; mt < 2; ++mt) {                                          \
        const char* rb = (const char*)&As[BUF][wm * 32 + mt * 16 + c][0];     \
        f32x4 r0 = *(const f32x4*)(rb + (((2 * g) ^ (c & 7)) << 4));          \
        f32x4 r1 = *(const f32x4*)(rb + (((2 * g + 1) ^ (c & 7)) << 4));      \
        union { bf16_t h[8]; bf16x8 v; } u_;                                  \
        for (int j = 0; j < 4; ++j) {                                         \
            u_.h[j]     = (bf16_t)r0[j];                                      \
            u_.h[4 + j] = (bf16_t)r1[j];                                      \
        }                                                                     \
        for (int nt = 0; nt < 6; ++nt)                                        \
            acc[mt][nt] = MFMA16(u_.v, w[S][nt], acc[mt][nt]);                \
    } } while (0)

    // prologue
    STAGE(0, 0);
    WLOAD(0, 0);
    __syncthreads();

    for (int tt = 0; tt < 32; tt += 2) {
        STAGE(1, tt + 1);                        // issue next stage FIRST
        WLOAD(1, tt + 1);
        COMPUTE(0, 0);
        __syncthreads();                         // vmcnt0: buf1 ready

        if (tt + 2 < 32) {
            STAGE(0, tt + 2);
            WLOAD(0, tt + 2);
        }
        COMPUTE(1, 1);
        __syncthreads();
    }
#undef STAGE
#undef WLOAD
#undef COMPUTE

    const float sc = 0.08838834764831845f * 1.4426950408889634f; // 1/sqrt(128)*log2e
    for (int mt = 0; mt < 2; ++mt)
        for (int nt = 0; nt < 6; ++nt) {
            int cb = nhalf * 192 + wn * 96 + nt * 16;
            int w_ = cb >> 7;
            int hl = (cb & 127) + c;             // col within Q/K/V
            int t0 = row0 + wm * 32 + mt * 16 + g * 4;  // global row
            if (w_ == 2) {
                int b  = t0 >> 11;
                int ttr = t0 & (TT - 1);
                int vc = ttr >> 5, gg = (ttr & 31) >> 3, j0 = ttr & 7;
                int hb = hl >> 4, cc = hl & 15;
                union { bf16_t h4[4]; unsigned long long u; } pk;
                for (int i = 0; i < 4; ++i) pk.h4[i] = (bf16_t)acc[mt][nt][i];
                *reinterpret_cast<unsigned long long*>(
                    Vf + ((size_t)((b * 64 + vc) * 8 + hb)) * 512 +
                    (gg * 16 + cc) * 8 + j0) = pk.u;
            } else {
                bf16_t* dst = (w_ == 0) ? Qf : Kf;
                float s = (w_ == 0) ? sc : 1.0f;
                int kk = hl >> 5, gg = (hl & 31) >> 3, e = hl & 7;
                int grt = t0 >> 4;
                for (int i = 0; i < 4; ++i) {
                    int cr = (t0 + i) & 15;
                    dst[((size_t)(grt * 4 + kk)) * 512 + (gg * 16 + cr) * 8 + e] =
                        (bf16_t)(acc[mt][nt][i] * s);
                }
            }
        }
}

// ---------------- flash attention, split-KV partials, fragment-major I/O ----------------
// unit = (b, 32-row qtile, kvchunk256); one wave per unit, 4 units/block.
// blockIdx&7 = b -> XCD-pinned batch. Every Q/K/V load = 1 coalesced 1KB instr.
__global__ __launch_bounds__(256) void attn_kernel(
    const bf16_t* __restrict__ Qf, const bf16_t* __restrict__ Kf,
    const bf16_t* __restrict__ Vf, bf16_t* __restrict__ Pacc,
    float* __restrict__ Pml)
{
    __shared__ __attribute__((aligned(16))) bf16_t Pl[4][32][40];
    const int tid = threadIdx.x, lane = tid & 63, wid = tid >> 6;
    const int g = lane >> 4, c = lane & 15;
    bf16_t (*P)[40] = Pl[wid];

    const int bx = blockIdx.x;
    const int b  = bx & 7;                       // XCD-pinned batch
    const int u  = 287 - ((bx >> 3) * 4 + wid);  // long-units-first
    int k = 0;
    while (4 * (k + 1) * (k + 2) <= u) ++k;      // tier k = qt>>3, 0..7
    const int r  = u - 4 * k * (k + 1);
    const int qt = 8 * k + r / (k + 1);
    const int ch = r - (r / (k + 1)) * (k + 1);
    const int q0 = qt * 32;
    const int kv_lo = ch * 256;
    int kv_hi = kv_lo + 256; if (kv_hi > q0 + 32) kv_hi = q0 + 32;
    const int sid = b * UPB + 4 * k * (k + 1) + (qt & 7) * (k + 1) + ch;

    bf16x8 qA[4], qB[4];
    for (int kk = 0; kk < 4; ++kk) {
        qA[kk] = *(const bf16x8*)(Qf +
            ((size_t)((b * 128 + (q0 >> 4)) * 4 + kk)) * 512 + lane * 8);
        qB[kk] = *(const bf16x8*)(Qf +
            ((size_t)((b * 128 + (q0 >> 4) + 1) * 4 + kk)) * 512 + lane * 8);
    }

    f32x4 accA[8], accB[8];
    for (int hb = 0; hb < 8; ++hb) { accA[hb] = (f32x4)0.0f; accB[hb] = (f32x4)0.0f; }
    float lsA[4] = {0, 0, 0, 0}, lsB[4] = {0, 0, 0, 0};

    for (int kv0 = kv_lo; kv0 < kv_hi; kv0 += 32) {
        const int kt = b * 128 + (kv0 >> 4);
        bf16x8 k0f[4], k1f[4], vf[8];
        for (int kk = 0; kk < 4; ++kk) {
            k0f[kk] = *(const bf16x8*)(Kf + ((size_t)(kt * 4 + kk)) * 512 + lane * 8);
            k1f[kk] = *(const bf16x8*)(Kf + ((size_t)((kt + 1) * 4 + kk)) * 512 + lane * 8);
        }
        const int vcb = (b * 64 + (kv0 >> 5)) * 8;
        for (int hb = 0; hb < 8; ++hb)
            vf[hb] = *(const bf16x8*)(Vf + ((size_t)(vcb + hb)) * 512 + lane * 8);

        f32x4 sA0 = (f32x4)0.0f, sA1 = (f32x4)0.0f;
        f32x4 sB0 = (f32x4)0.0f, sB1 = (f32x4)0.0f;
        for (int kk = 0; kk < 4; ++kk) {
            sA0 = MFMA16(qA[kk], k0f[kk], sA0);
            sA1 = MFMA16(qA[kk], k1f[kk], sA1);
            sB0 = MFMA16(qB[kk], k0f[kk], sB0);
            sB1 = MFMA16(qB[kk], k1f[kk], sB1);
        }
        if (kv0 + 32 > q0) {                     // causal mask, subtile A
            for (int i = 0; i < 4; ++i) {
                int row = q0 + g * 4 + i;
                if (kv0 + c > row)      sA0[i] = -1e30f;
                if (kv0 + 16 + c > row) sA1[i] = -1e30f;
            }
        }
        if (kv0 + 32 > q0 + 16) {                // causal mask, subtile B
            for (int i = 0; i < 4; ++i) {
                int row = q0 + 16 + g * 4 + i;
                if (kv0 + c > row)      sB0[i] = -1e30f;
                if (kv0 + 16 + c > row) sB1[i] = -1e30f;
            }
        }
        float pA0[4], pA1[4], pB0[4], pB1[4];
        for (int i = 0; i < 4; ++i) {            // p = 2^s (log2e folded into Q)
            pA0[i] = exp2f(sA0[i]); pA1[i] = exp2f(sA1[i]);
            pB0[i] = exp2f(sB0[i]); pB1[i] = exp2f(sB1[i]);
            lsA[i] += pA0[i] + pA1[i];
            lsB[i] += pB0[i] + pB1[i];
        }
        for (int i = 0; i < 4; ++i) {
            P[g * 4 + i][c]           = (bf16_t)pA0[i];
            P[g * 4 + i][c + 16]      = (bf16_t)pA1[i];
            P[16 + g * 4 + i][c]      = (bf16_t)pB0[i];
            P[16 + g * 4 + i][c + 16] = (bf16_t)pB1[i];
        }
        __builtin_amdgcn_wave_barrier();
        asm volatile("s_waitcnt lgkmcnt(0)" ::: "memory");
        __builtin_amdgcn_sched_barrier(0);
        bf16x8 paA = *(const bf16x8*)&P[c][g * 8];
        bf16x8 paB = *(const bf16x8*)&P[16 + c][g * 8];
        __builtin_amdgcn_s_setprio(1);
        for (int hb = 0; hb < 8; ++hb) {
            accA[hb] = MFMA16(paA, vf[hb], accA[hb]);
            accB[hb] = MFMA16(paB, vf[hb], accB[hb]);
        }
        __builtin_amdgcn_s_setprio(0);
        __builtin_amdgcn_wave_barrier();
    }

    for (int off = 1; off < 16; off <<= 1)
        for (int i = 0; i < 4; ++i) {
            lsA[i] += __shfl_xor(lsA[i], off, 64);
            lsB[i] += __shfl_xor(lsB[i], off, 64);
        }
    if (c == 0)
        for (int i = 0; i < 4; ++i) {
            Pml[(size_t)sid * 32 + g * 4 + i]      = lsA[i];
            Pml[(size_t)sid * 32 + 16 + g * 4 + i] = lsB[i];
        }

    // Pacc transposed: po[col=128][row=32]; packed 8B stores
    bf16_t* po = Pacc + (size_t)sid * (32 * 128);
    for (int hb = 0; hb < 8; ++hb) {
        union { bf16_t h4[4]; unsigned long long u; } pa, pb;
        for (int i = 0; i < 4; ++i) {
            pa.h4[i] = (bf16_t)accA[hb][i];
            pb.h4[i] = (bf16_t)accB[hb][i];
        }
        bf16_t* cp = po + (hb * 16 + c) * 32;
        *reinterpret_cast<unsigned long long*>(cp + g * 4)      = pa.u;
        *reinterpret_cast<unsigned long long*>(cp + 16 + g * 4) = pb.u;
    }
}

// ---------------- combine partials (plain sums; Pacc is [col][row]) ----------------
__global__ __launch_bounds__(128) void combine_kernel(
    const bf16_t* __restrict__ Pacc, const float* __restrict__ Pml,
    float* __restrict__ out)
{
    __shared__ float invL[32];
    const int qt = blockIdx.x;                   // 0..63
    const int b  = blockIdx.y;
    const int k  = qt >> 3;
    const int base  = b * UPB + 4 * k * (k + 1) + (qt & 7) * (k + 1);
    const int count = k + 1;
    const int tid = threadIdx.x;                 // = col 0..127

    if (tid < 32) {
        float L = 0.0f;
        for (int cu = 0; cu < count; ++cu)
            L += Pml[(size_t)(base + cu) * 32 + tid];
        invL[tid] = 1.0f / L;
    }
    __syncthreads();

    float s[32];
    for (int r = 0; r < 32; ++r) s[r] = 0.0f;
    for (int cu = 0; cu < count; ++cu) {
        const bf16_t* cp = Pacc + (size_t)(base + cu) * 4096 + tid * 32;
        for (int r8 = 0; r8 < 4; ++r8) {
            bf16x8 v = *(const bf16x8*)(cp + r8 * 8);
            for (int j = 0; j < 8; ++j) s[r8 * 8 + j] += (float)v[j];
        }
    }
    const int q0 = qt * 32;
    for (int r = 0; r < 32; ++r)
        out[((size_t)b * TT + q0 + r) * HH + tid] = s[r] * invL[r];
}

extern "C" void kernel_launch(void* const* d_in, const int* in_sizes, int n_in,
                              void* d_out, int out_size, void* d_ws, size_t ws_size,
                              hipStream_t stream)
{
    const float* x  = (const float*)d_in[0];
    const float* Wq = (const float*)d_in[1];
    const float* Wk = (const float*)d_in[2];
    const float* Wv = (const float*)d_in[3];

    char* ws = (char*)d_ws;
    bf16_t* Wf   = (bf16_t*)ws;                       // 768 KB fragment-major
    bf16_t* Qf   = (bf16_t*)(ws + (1u  << 20));       // 4 MB fragment-major
    bf16_t* Kf   = (bf16_t*)(ws + (5u  << 20));       // 4 MB fragment-major
    bf16_t* Vf   = (bf16_t*)(ws + (9u  << 20));       // 4 MB fragment-major
    bf16_t* Pacc = (bf16_t*)(ws + (13u << 20));       // 2304*8192 B = 18.9 MB
    float*  Pml  = (float*) (ws + (32u << 20));       // 2304*128 B

    prep_w_kernel<<<1536, 256, 0, stream>>>(Wq, Wk, Wv, Wf);
    qkv_kernel<<<512, 256, 0, stream>>>(x, Wf, Qf, Kf, Vf);
    attn_kernel<<<576, 256, 0, stream>>>(Qf, Kf, Vf, Pacc, Pml);
    combine_kernel<<<dim3(64, 8), 128, 0, stream>>>(Pacc, Pml, (float*)d_out);
}